// Round 1
// 802.622 us; speedup vs baseline: 1.0284x; 1.0284x over previous
//
#include <hip/hip_runtime.h>
#include <math.h>

// ---------------------------------------------------------------------------
// G2GDecoder forward loss on MI355X — R7: LDS-staged B operands.
//
// R6 was cache-BW-bound: every wave re-fetched every B fragment from L2/L3
// (~3.1 GB/iter of fragment traffic). R7 stages B tiles into LDS once per
// block (shared by 4 waves), double-buffered with counted vmcnt (stage kc+1
// overlaps compute kc), and fuses strips sharing the same A (kB: 3 weights,
// kD: 2 weights). B tiles are chunk-swizzled at prep time so the linear
// global_load_lds write + swizzled ds_read_b128 read is 2-way-bank (free).
// ---------------------------------------------------------------------------

#define BGR   1024
#define NT    51200
#define NG    61440
#define NE    100352
#define NELG  200704
#define D     450
#define DP    452       // fp32 intermediate row stride
#define KP_D  480       // bf16 K-pad for D-dim (mult of 32); ldT = 15
#define KP_V  800       // bf16 K-pad for vocab (780);        ldT = 25
#define CATP  1440      // 3*480 concat (segs at 0,480,960);  ldT = 45
#define VOCAB 780
#define VP    784
#define CAP   4096      // task cap; E[T]~2048
#define NROWA 5120      // BGR+CAP rows allocated for idoh/f planes
#define WT_N  512       // padded col count for D-out weights (32 col-tiles)
#define WT_NV 832       // padded col count for u_l (52 col-tiles)

typedef unsigned short u16;
typedef short bf16x8 __attribute__((ext_vector_type(8)));
typedef float f32x4 __attribute__((ext_vector_type(4)));

__device__ __forceinline__ float sigmoidf_(float x) { return 1.0f / (1.0f + expf(-x)); }
__device__ __forceinline__ float softplusf_(float x) {
    return fmaxf(x, 0.0f) + log1pf(expf(-fabsf(x)));   // == jax.nn.softplus
}
__device__ __forceinline__ int lower_bound_i(const int* __restrict__ a, int n, int v) {
    int lo = 0, hi = n;
    while (lo < hi) { int mid = (lo + hi) >> 1; if (a[mid] < v) lo = mid + 1; else hi = mid; }
    return lo;
}
__device__ __forceinline__ u16 f2bf(float x) {
    unsigned u = __float_as_uint(x);
    return (u16)((u + 0x7FFFu + ((u >> 16) & 1u)) >> 16);   // RNE
}
__device__ __forceinline__ float bf2f(u16 h) { return __uint_as_float(((unsigned)h) << 16); }
__device__ __forceinline__ void split2(float x, u16& h, u16& l) {
    h = f2bf(x); l = f2bf(x - bf2f(h));
}
__device__ __forceinline__ float dot4(float4 a, float4 b) {
    return fmaf(a.x, b.x, fmaf(a.y, b.y, fmaf(a.z, b.z, a.w * b.w)));
}
// fragment-tiled offset for logical (row, k) with ldT = Kp/32 tiles per row-strip
__device__ __forceinline__ size_t frag_off(int ldT, int row, int k) {
    return (((size_t)(row >> 4) * ldT + (k >> 5)) << 9) + ((row & 15) << 5) + (k & 31);
}
// Swizzled within-tile u16 index for logical (colLocal, kLocal) of a B tile.
// 16B chunk index (k>>3) is XOR'd with (col>>1)&3: linear global_load_lds
// staging preserves it, and the ds_read_b128 pattern below lands at uniform
// 2-way bank aliasing (free) instead of 8-way.
__device__ __forceinline__ int bswz(int colL, int kL) {
    return (colL << 5) + ((((kL >> 3) ^ ((colL >> 1) & 3)) & 3) << 3) + (kL & 7);
}

#define GLOAD_LDS16(SRC, DST)                                                   \
    __builtin_amdgcn_global_load_lds(                                           \
        (const __attribute__((address_space(1))) unsigned int*)(const void*)(SRC), \
        (__attribute__((address_space(3))) unsigned int*)(void*)(DST), 16, 0, 0)

// ---------------------------------------------------------------------------
// LDS-staged strip: block = 256 thr / 4 waves; each wave one rowTile (16 rows);
// all 4 waves share the same ctBase (4 col-tiles = 64 cols) and NW B-matrices
// (which share the A operand). Per kc, the NW*8 B tiles (hi+lo planes x 4 ct)
// are staged cooperatively into LDS (1KB contiguous tile each, depth-1 dbuf).
// acc[n][c][r]: row = rowTile*16 + (lane>>4)*4 + r, col = (ctBase+c)*16 + (lane&15).
template <int NW>
__device__ __forceinline__ void mfma_strip_lds(
    const u16* Ah, const u16* Al, int ldTA, int rowTile,
    const u16* Wh0, const u16* Wl0, const u16* Wh1, const u16* Wl1,
    const u16* Wh2, const u16* Wl2,
    int ldTW, int ctBase, int nKc, u16* lds, f32x4 (&acc)[NW][4]) {
    int lane = threadIdx.x & 63, wave = threadIdx.x >> 6;
    int m = lane & 15, q = lane >> 4;
    int lo = (m << 5) + (q << 3);
    const u16* pah = Ah + (((size_t)rowTile * ldTA) << 9) + lo;
    const u16* pal = Al + (((size_t)rowTile * ldTA) << 9) + lo;
    // swizzled read offset (bytes) within a staged 1KB tile
    int boff = (m << 6) + (((q ^ ((m >> 1) & 3)) & 3) << 4);
    auto stage = [&](int kc, int buf) {
#pragma unroll
        for (int t = 0; t < 2 * NW; ++t) {
            int tile = wave + 4 * t;                 // 0 .. NW*8-1, wave-uniform
            int n = tile >> 3, c = (tile >> 1) & 3, pl = tile & 1;
            const u16* wp = (n == 0) ? (pl ? Wl0 : Wh0)
                          : (n == 1) ? (pl ? Wl1 : Wh1)
                                     : (pl ? Wl2 : Wh2);
            const u16* src = wp + ((((size_t)(ctBase + c)) * ldTW + kc) << 9) + (lane << 3);
            u16* dst = lds + (((size_t)(buf * NW * 8 + tile)) << 9);
            GLOAD_LDS16(src, dst);                   // 64 lanes x 16B = 1KB tile
        }
    };
    stage(0, 0);
    for (int kc = 0; kc < nKc; ++kc) {
        if (kc + 1 < nKc) {
            stage(kc + 1, (kc + 1) & 1);
            // leave stage(kc+1)'s 2*NW loads in flight; drain stage(kc)
            asm volatile("s_waitcnt vmcnt(%0)" :: "n"(2 * NW) : "memory");
        } else {
            asm volatile("s_waitcnt vmcnt(0)" ::: "memory");
        }
        __builtin_amdgcn_s_barrier();
        asm volatile("" ::: "memory");               // keep ds_reads below barrier
        bf16x8 aH = *(const bf16x8*)(pah + ((size_t)kc << 9));
        bf16x8 aL = *(const bf16x8*)(pal + ((size_t)kc << 9));
        const u16* tb = lds + (((size_t)((kc & 1) * NW * 8)) << 9);
#pragma unroll
        for (int n = 0; n < NW; ++n) {
#pragma unroll
            for (int c = 0; c < 4; ++c) {
                const char* bt = (const char*)(tb + (((n << 3) + (c << 1)) << 9));
                bf16x8 bH = *(const bf16x8*)(bt + boff);
                bf16x8 bL = *(const bf16x8*)(bt + 1024 + boff);
                acc[n][c] = __builtin_amdgcn_mfma_f32_16x16x32_bf16(aH, bH, acc[n][c], 0, 0, 0);
                acc[n][c] = __builtin_amdgcn_mfma_f32_16x16x32_bf16(aH, bL, acc[n][c], 0, 0, 0);
                acc[n][c] = __builtin_amdgcn_mfma_f32_16x16x32_bf16(aL, bH, acc[n][c], 0, 0, 0);
            }
        }
        asm volatile("" ::: "memory");               // all reads done before restage
        __builtin_amdgcn_s_barrier();
        asm volatile("" ::: "memory");
    }
}

// ---------------------------------------------------------------------------
// Weight prep: dst tiled [colTile][kc] with col from src's N-dim (transpose),
// k range [kOff, kOff+kLen) of a KpTot-deep stacked buffer. Chunk-swizzled.
struct WJob { const float* src; int srcK, srcN, KpTot, kOff, kLen, NA, dstOff, cum; };
struct WArgs { WJob j[16]; int total; };

__global__ void k_prepw(WArgs a, u16* __restrict__ whi, u16* __restrict__ wlo) {
    int idx = blockIdx.x * blockDim.x + threadIdx.x;
    int stride = gridDim.x * blockDim.x;
    for (; idx < a.total; idx += stride) {
        int jj = 0;
        while (jj < 15 && idx >= a.j[jj + 1].cum) ++jj;
        WJob J = a.j[jj];
        int local = idx - J.cum;
        int t = local >> 9, w = local & 511;
        int nKc = J.kLen >> 5;
        int ct = t / nKc, kcL = t - ct * nKc;
        int col = ct * 16 + (w >> 5);
        int kk = kcL * 32 + (w & 31);
        float v = (kk < J.srcK && col < J.srcN) ? J.src[(size_t)kk * J.srcN + col] : 0.f;
        u16 h, l; split2(v, h, l);
        size_t pos = (size_t)J.dstOff
                   + (((size_t)(ct * (J.KpTot >> 5) + (J.kOff >> 5) + kcL)) << 9)
                   + bswz(w >> 5, w & 31);
        whi[pos] = h; wlo[pos] = l;
    }
}

__global__ void k_init(float* __restrict__ sumh, int* __restrict__ root_slot,
                       int* __restrict__ counter, float* __restrict__ dl,
                       float* __restrict__ out) {
    int i = blockIdx.x * blockDim.x + threadIdx.x;
    if (i < BGR * DP) sumh[i] = 0.0f;
    if (i < NE) root_slot[i] = -1;
    if (i < BGR) dl[i] = 0.0f;
    if (i == 0) counter[0] = 0;
    if (i < 2) out[i] = 0.0f;
}

__global__ void k_scatter_roots(const int* __restrict__ root_eids, int* __restrict__ root_slot) {
    int b = blockIdx.x * blockDim.x + threadIdx.x;
    if (b < BGR) root_slot[root_eids[b]] = b;   // duplicate roots share one slot
}

__global__ void k_build_tasks(const int* __restrict__ lg_src, const int* __restrict__ lg_dst,
                              const int* __restrict__ edge_src, const int* __restrict__ root_slot,
                              int2* __restrict__ tasks, int* __restrict__ counter) {
    int j = blockIdx.x * blockDim.x + threadIdx.x;
    if (j < NELG) {
        int r = root_slot[lg_dst[j]];
        if (r >= 0) {
            int idx = atomicAdd(counter, 1);
            if (idx < CAP) tasks[idx] = make_int2(edge_src[lg_src[j]], r);
        }
    }
}

// Gather id_onehot rows (roots then tasks) -> tiled hi/lo planes [NROWA x KP_V].
// A-operand layout: linear (NOT swizzled).
__global__ void k_gather_idoh(
    const float* __restrict__ id_onehot, const int* __restrict__ edge_src,
    const int* __restrict__ root_eids, const int2* __restrict__ tasks,
    const int* __restrict__ counter, u16* __restrict__ ih, u16* __restrict__ il) {
    int T = counter[0]; if (T > CAP) T = CAP;
    int nRows = BGR + T;
    long total = (long)NROWA * KP_V;
    long idx = (long)(blockIdx.x * blockDim.x + threadIdx.x);
    long stride = (long)gridDim.x * blockDim.x;
    for (; idx < total; idx += stride) {
        int t = (int)(idx >> 9), w = (int)(idx & 511);
        int rt = t / 25, kc = t - rt * 25;
        int row = rt * 16 + (w >> 5), k = kc * 32 + (w & 31);
        float v = 0.f;
        if (row < nRows && k < VOCAB) {
            int n = (row < BGR) ? edge_src[root_eids[row]] : tasks[row - BGR].x;
            v = id_onehot[(size_t)n * VOCAB + k];
        }
        u16 h, l; split2(v, h, l);
        ih[idx] = h; il[idx] = l;
    }
}

// Gather sumh rows by root slot -> tiled hi/lo [1024 x KP_D]. (A-operand, linear.)
__global__ void k_conv_sumh(
    const float* __restrict__ sumh, const int* __restrict__ root_slot,
    const int* __restrict__ root_eids, u16* __restrict__ sh, u16* __restrict__ sl) {
    int idx = blockIdx.x * blockDim.x + threadIdx.x;
    if (idx >= BGR * KP_D) return;
    int t = idx >> 9, w = idx & 511;
    int rt = t / 15, kc = t - rt * 15;
    int row = rt * 16 + (w >> 5), k = kc * 32 + (w & 31);
    int slot = root_slot[root_eids[row]];
    float v = (k < D) ? sumh[(size_t)slot * DP + k] : 0.f;
    u16 h, l; split2(v, h, l);
    sh[idx] = h; sl[idx] = l;
}

// ---------------------------------------------------------------------------
// kA: f[row] = idoh[row] @ emb -> f tiled [NROWA x KP_D]
__global__ __launch_bounds__(256) void kA(
    const u16* __restrict__ ih, const u16* __restrict__ il,
    const u16* __restrict__ eTh, const u16* __restrict__ eTl,
    const int* __restrict__ counter, u16* __restrict__ fH, u16* __restrict__ fL) {
    __shared__ __align__(1024) u16 lds[2 * 8 * 512];
    int T = counter[0]; if (T > CAP) T = CAP;
    int nRows = BGR + T;
    int rowBase = blockIdx.x * 64; if (rowBase >= nRows) return;
    int ctBase = blockIdx.y * 4;
    int rowTile = (rowBase >> 4) + (threadIdx.x >> 6);
    f32x4 z4 = {0.f, 0.f, 0.f, 0.f};
    f32x4 acc[1][4] = {{z4, z4, z4, z4}};
    mfma_strip_lds<1>(ih, il, 25, rowTile, eTh, eTl, nullptr, nullptr, nullptr, nullptr,
                      25, ctBase, 25, lds, acc);
    int lane = threadIdx.x & 63, m = lane & 15, q = lane >> 4;
#pragma unroll
    for (int c = 0; c < 4; ++c) {
        int col = (ctBase + c) * 16 + m;
        if (col >= KP_D) continue;
#pragma unroll
        for (int r = 0; r < 4; ++r) {
            int row = rowTile * 16 + q * 4 + r;
            size_t o = frag_off(15, row, col);
            u16 h, l; split2(acc[0][c][r], h, l);
            fH[o] = h; fL[o] = l;
        }
    }
}

// kB: z=f@wz, hh=f@w_h (+ fw1=f@w_d1 for root tiles) — one fused pass, A loaded
// once. Roots -> msg into catl seg0 (tiled) + fw1 (fp32); tasks -> atomic sumh.
__global__ __launch_bounds__(256) void kB(
    const u16* __restrict__ fH, const u16* __restrict__ fL,
    const u16* __restrict__ wzTh, const u16* __restrict__ wzTl,
    const u16* __restrict__ whTh, const u16* __restrict__ whTl,
    const u16* __restrict__ wd1Th, const u16* __restrict__ wd1Tl,
    const float* __restrict__ bz, const float* __restrict__ b_h,
    const int2* __restrict__ tasks, const int* __restrict__ counter,
    u16* __restrict__ clH, u16* __restrict__ clL,
    float* __restrict__ fw1, float* __restrict__ sumh) {
    __shared__ __align__(1024) u16 lds[2 * 3 * 8 * 512];
    int T = counter[0]; if (T > CAP) T = CAP;
    int nRows = BGR + T;
    int rowBase = blockIdx.x * 64; if (rowBase >= nRows) return;
    int ctBase = blockIdx.y * 4;
    int rowTile = (rowBase >> 4) + (threadIdx.x >> 6);
    bool isRoot = rowBase < BGR;
    int lane = threadIdx.x & 63, m = lane & 15, q = lane >> 4;
    f32x4 z4 = {0.f, 0.f, 0.f, 0.f};
    if (isRoot) {
        f32x4 acc[3][4] = {{z4, z4, z4, z4}, {z4, z4, z4, z4}, {z4, z4, z4, z4}};
        mfma_strip_lds<3>(fH, fL, 15, rowTile, wzTh, wzTl, whTh, whTl, wd1Th, wd1Tl,
                          15, ctBase, 15, lds, acc);
#pragma unroll
        for (int c = 0; c < 4; ++c) {
            int col = (ctBase + c) * 16 + m;
            if (col >= KP_D) continue;
            float bzv = (col < D) ? bz[col] : 0.f;
            float bhv = (col < D) ? b_h[col] : 0.f;
#pragma unroll
            for (int r = 0; r < 4; ++r) {
                int row = rowTile * 16 + q * 4 + r;
                float v = (col < D) ? sigmoidf_(acc[0][c][r] + bzv) * tanhf(acc[1][c][r] + bhv) : 0.f;
                size_t o = frag_off(45, row, col);   // catl seg0: k = col
                u16 h, l; split2(v, h, l);
                clH[o] = h; clL[o] = l;
                if (col < D) fw1[(size_t)row * DP + col] = acc[2][c][r];
            }
        }
    } else {
        f32x4 acc[2][4] = {{z4, z4, z4, z4}, {z4, z4, z4, z4}};
        mfma_strip_lds<2>(fH, fL, 15, rowTile, wzTh, wzTl, whTh, whTl, nullptr, nullptr,
                          15, ctBase, 15, lds, acc);
#pragma unroll
        for (int c = 0; c < 4; ++c) {
            int col = (ctBase + c) * 16 + m;
            if (col >= D) continue;
            float bzv = bz[col], bhv = b_h[col];
#pragma unroll
            for (int r = 0; r < 4; ++r) {
                int row = rowTile * 16 + q * 4 + r;
                if (row < nRows) {
                    float v = sigmoidf_(acc[0][c][r] + bzv) * tanhf(acc[1][c][r] + bhv);
                    int slot = tasks[row - BGR].y;
                    atomicAdd(&sumh[(size_t)slot * DP + col], v);
                }
            }
        }
    }
}

// kC: hroot = relu(fw1 + sumhs@w_d2 + b_d1) -> catd seg0 (tiled)
__global__ __launch_bounds__(256) void kC(
    const u16* __restrict__ sH, const u16* __restrict__ sL,
    const u16* __restrict__ wTh, const u16* __restrict__ wTl,
    const float* __restrict__ fw1, const float* __restrict__ b_d1,
    u16* __restrict__ cdH, u16* __restrict__ cdL) {
    __shared__ __align__(1024) u16 lds[2 * 8 * 512];
    int ctBase = blockIdx.y * 4;
    int rowTile = (blockIdx.x * 64 >> 4) + (threadIdx.x >> 6);
    f32x4 z4 = {0.f, 0.f, 0.f, 0.f};
    f32x4 acc[1][4] = {{z4, z4, z4, z4}};
    mfma_strip_lds<1>(sH, sL, 15, rowTile, wTh, wTl, nullptr, nullptr, nullptr, nullptr,
                      15, ctBase, 15, lds, acc);
    int lane = threadIdx.x & 63, m = lane & 15, q = lane >> 4;
#pragma unroll
    for (int c = 0; c < 4; ++c) {
        int col = (ctBase + c) * 16 + m;
        if (col >= KP_D) continue;
        float bd = (col < D) ? b_d1[col] : 0.f;
#pragma unroll
        for (int r = 0; r < 4; ++r) {
            int row = rowTile * 16 + q * 4 + r;
            float v = 0.f;
            if (col < D) v = fmaxf(fw1[(size_t)row * DP + col] + acc[0][c][r] + bd, 0.f);
            size_t o = frag_off(45, row, col);
            u16 h, l; split2(v, h, l);
            cdH[o] = h; cdL[o] = l;
        }
    }
}

// kD: job0: catd seg0 @ {a_dT,a_dG} -> qdT,qdG ; job1: catl seg0 @ {a_lT,a_lG}
// (two B-matrices fused per pass; A loaded once)
__global__ __launch_bounds__(256) void kD(
    const u16* __restrict__ cdH, const u16* __restrict__ cdL,
    const u16* __restrict__ clH, const u16* __restrict__ clL,
    const u16* __restrict__ aTh0, const u16* __restrict__ aTl0,
    const u16* __restrict__ aGh0, const u16* __restrict__ aGl0,
    const u16* __restrict__ aTh1, const u16* __restrict__ aTl1,
    const u16* __restrict__ aGh1, const u16* __restrict__ aGl1,
    float* __restrict__ qdT, float* __restrict__ qdG,
    float* __restrict__ qlT, float* __restrict__ qlG) {
    __shared__ __align__(1024) u16 lds[2 * 2 * 8 * 512];
    int ctBase = blockIdx.y * 4, job = blockIdx.z;
    int rowTile = (blockIdx.x * 64 >> 4) + (threadIdx.x >> 6);
    const u16* Ahp = job ? clH : cdH;
    const u16* Alp = job ? clL : cdL;
    f32x4 z4 = {0.f, 0.f, 0.f, 0.f};
    f32x4 acc[2][4] = {{z4, z4, z4, z4}, {z4, z4, z4, z4}};
    mfma_strip_lds<2>(Ahp, Alp, 45, rowTile,
                      job ? aTh1 : aTh0, job ? aTl1 : aTl0,
                      job ? aGh1 : aGh0, job ? aGl1 : aGl0,
                      nullptr, nullptr, 15, ctBase, 15, lds, acc);
    float* oT = job ? qlT : qdT;
    float* oG = job ? qlG : qdG;
    int lane = threadIdx.x & 63, m = lane & 15, q = lane >> 4;
#pragma unroll
    for (int c = 0; c < 4; ++c) {
        int col = (ctBase + c) * 16 + m;
        if (col >= D) continue;
#pragma unroll
        for (int r = 0; r < 4; ++r) {
            int row = rowTile * 16 + q * 4 + r;
            oT[(size_t)row * DP + col] = acc[0][c][r];
            oG[(size_t)row * DP + col] = acc[1][c][r];
        }
    }
}

// Fused dual attention, single-pass online softmax, float4 x-loads.
// Writes tiled bf16 into catd/catl segment (which=0 -> +480, which=1 -> +960).
__global__ __launch_bounds__(256) void k_att(
    const float* __restrict__ x_T, const float* __restrict__ x_G,
    const int* __restrict__ gid_T, const int* __restrict__ gid_G,
    const float* __restrict__ qdT, const float* __restrict__ qdG,
    const float* __restrict__ qlT, const float* __restrict__ qlG,
    u16* __restrict__ cdH, u16* __restrict__ cdL,
    u16* __restrict__ clH, u16* __restrict__ clL) {
    int bid = blockIdx.x, b = bid & (BGR - 1), which = bid >> 10;
    const float* x   = which ? x_G   : x_T;
    const int*   gid = which ? gid_G : gid_T;
    int N            = which ? NG    : NT;
    const float* qd  = (which ? qdG : qdT) + (size_t)b * DP;
    const float* ql  = (which ? qlG : qlT) + (size_t)b * DP;
    int K0 = 480 + which * 480;
    int tid = threadIdx.x, lane = tid & 63, wave = tid >> 6;
    __shared__ __align__(16) float s_qd[DP], s_ql[DP];
    __shared__ float s_m[4][2], s_z[4][2];
    __shared__ __align__(16) float s_acc[4][2][DP];
    for (int d = tid; d < DP; d += 256) {
        s_qd[d] = (d < D) ? qd[d] : 0.f;
        s_ql[d] = (d < D) ? ql[d] : 0.f;
    }
    int lo = lower_bound_i(gid, N, b), hi = lower_bound_i(gid, N, b + 1);
    __syncthreads();
    int g0 = lane, g1 = 64 + lane;
    bool g1ok = g1 < 112;                       // 112 full float4 groups (448)
    bool tok = (lane == 48) || (lane == 49);    // tail d = 448, 449
    int td = 448 + (lane - 48);
    float4 qd0 = *(const float4*)&s_qd[4 * g0];
    float4 ql0 = *(const float4*)&s_ql[4 * g0];
    float4 qd1 = g1ok ? *(const float4*)&s_qd[4 * g1] : make_float4(0, 0, 0, 0);
    float4 ql1 = g1ok ? *(const float4*)&s_ql[4 * g1] : make_float4(0, 0, 0, 0);
    float tqd = tok ? s_qd[td] : 0.f, tql = tok ? s_ql[td] : 0.f;
    float md = -INFINITY, ml = -INFINITY, zd = 0.f, zl = 0.f;
    float4 ad0 = make_float4(0, 0, 0, 0), ad1 = ad0, al0 = ad0, al1 = ad0;
    float atd = 0.f, atl = 0.f;
    for (int n = lo + wave; n < hi; n += 4) {
        const float* xr = x + (size_t)n * D;
        float4 v0 = *(const float4*)(xr + 4 * g0);
        float4 v1 = g1ok ? *(const float4*)(xr + 4 * g1) : make_float4(0, 0, 0, 0);
        float tv = tok ? xr[td] : 0.f;
        float pd = dot4(v0, qd0) + dot4(v1, qd1) + tv * tqd;
        float pl = dot4(v0, ql0) + dot4(v1, ql1) + tv * tql;
#pragma unroll
        for (int o = 32; o; o >>= 1) { pd += __shfl_xor(pd, o); pl += __shfl_xor(pl, o); }
        float nmd = fmaxf(md, pd), nml = fmaxf(ml, pl);
        float sd = expf(md - nmd), sl = expf(ml - nml);
        float ed = expf(pd - nmd), el = expf(pl - nml);
        zd = zd * sd + ed; zl = zl * sl + el;
        ad0.x = ad0.x * sd + ed * v0.x; ad0.y = ad0.y * sd + ed * v0.y;
        ad0.z = ad0.z * sd + ed * v0.z; ad0.w = ad0.w * sd + ed * v0.w;
        ad1.x = ad1.x * sd + ed * v1.x; ad1.y = ad1.y * sd + ed * v1.y;
        ad1.z = ad1.z * sd + ed * v1.z; ad1.w = ad1.w * sd + ed * v1.w;
        al0.x = al0.x * sl + el * v0.x; al0.y = al0.y * sl + el * v0.y;
        al0.z = al0.z * sl + el * v0.z; al0.w = al0.w * sl + el * v0.w;
        al1.x = al1.x * sl + el * v1.x; al1.y = al1.y * sl + el * v1.y;
        al1.z = al1.z * sl + el * v1.z; al1.w = al1.w * sl + el * v1.w;
        atd = atd * sd + ed * tv; atl = atl * sl + el * tv;
        md = nmd; ml = nml;
    }
    *(float4*)&s_acc[wave][0][4 * g0] = ad0;
    *(float4*)&s_acc[wave][1][4 * g0] = al0;
    if (g1ok) {
        *(float4*)&s_acc[wave][0][4 * g1] = ad1;
        *(float4*)&s_acc[wave][1][4 * g1] = al1;
    }
    if (tok) { s_acc[wave][0][td] = atd; s_acc[wave][1][td] = atl; }
    if (lane == 0) { s_m[wave][0] = md; s_m[wave][1] = ml; s_z[wave][0] = zd; s_z[wave][1] = zl; }
    __syncthreads();
    bool nonempty = (hi > lo);
    float Md = fmaxf(fmaxf(s_m[0][0], s_m[1][0]), fmaxf(s_m[2][0], s_m[3][0]));
    float Ml = fmaxf(fmaxf(s_m[0][1], s_m[1][1]), fmaxf(s_m[2][1], s_m[3][1]));
    float scd[4], scl[4];
#pragma unroll
    for (int w = 0; w < 4; ++w) { scd[w] = expf(s_m[w][0] - Md); scl[w] = expf(s_m[w][1] - Ml); }
    float Zd = s_z[0][0] * scd[0] + s_z[1][0] * scd[1] + s_z[2][0] * scd[2] + s_z[3][0] * scd[3];
    float Zl = s_z[0][1] * scl[0] + s_z[1][1] * scl[1] + s_z[2][1] * scl[2] + s_z[3][1] * scl[3];
    for (int d = tid; d < KP_D; d += 256) {
        float av = 0.f, lv = 0.f;
        if (d < D && nonempty) {
            av = (s_acc[0][0][d] * scd[0] + s_acc[1][0][d] * scd[1]
                + s_acc[2][0][d] * scd[2] + s_acc[3][0][d] * scd[3]) / Zd;
            lv = (s_acc[0][1][d] * scl[0] + s_acc[1][1][d] * scl[1]
                + s_acc[2][1][d] * scl[2] + s_acc[3][1][d] * scl[3]) / Zl;
        }
        size_t o = frag_off(45, b, K0 + d);
        u16 h, l;
        split2(av, h, l); cdH[o] = h; cdL[o] = l;
        split2(lv, h, l); clH[o] = h; clL[o] = l;
    }
}

// kEF: job0 topo head (K=1440 -> relu.u_d partial dot -> dl); job1 label hidden.
__global__ __launch_bounds__(256) void kEF(
    const u16* __restrict__ cdH, const u16* __restrict__ cdL,
    const u16* __restrict__ clH, const u16* __restrict__ clL,
    const u16* __restrict__ wdTh, const u16* __restrict__ wdTl,
    const u16* __restrict__ wlTh, const u16* __restrict__ wlTl,
    const float* __restrict__ b_d2, const float* __restrict__ u_d,
    const float* __restrict__ b_l1,
    u16* __restrict__ hlH, u16* __restrict__ hlL, float* __restrict__ dl) {
    __shared__ __align__(1024) u16 lds[2 * 8 * 512];
    int ctBase = blockIdx.y * 4, job = blockIdx.z;
    int rowTile = (blockIdx.x * 64 >> 4) + (threadIdx.x >> 6);
    f32x4 z4 = {0.f, 0.f, 0.f, 0.f};
    f32x4 acc[1][4] = {{z4, z4, z4, z4}};
    mfma_strip_lds<1>(job ? clH : cdH, job ? clL : cdL, 45, rowTile,
                      job ? wlTh : wdTh, job ? wlTl : wdTl,
                      nullptr, nullptr, nullptr, nullptr, 45, ctBase, 45, lds, acc);
    int lane = threadIdx.x & 63, m = lane & 15, q = lane >> 4;
    if (job) {
#pragma unroll
        for (int c = 0; c < 4; ++c) {
            int col = (ctBase + c) * 16 + m;
            if (col >= KP_D) continue;
            float b1 = (col < D) ? b_l1[col] : 0.f;
#pragma unroll
            for (int r = 0; r < 4; ++r) {
                int row = rowTile * 16 + q * 4 + r;
                float v = (col < D) ? fmaxf(acc[0][c][r] + b1, 0.f) : 0.f;
                size_t o = frag_off(15, row, col);
                u16 h, l; split2(v, h, l);
                hlH[o] = h; hlL[o] = l;
            }
        }
    } else {
#pragma unroll
        for (int r = 0; r < 4; ++r) {
            float pr = 0.f;
#pragma unroll
            for (int c = 0; c < 4; ++c) {
                int col = (ctBase + c) * 16 + m;
                if (col < D) pr += fmaxf(acc[0][c][r] + b_d2[col], 0.f) * u_d[col];
            }
#pragma unroll
            for (int o = 1; o < 16; o <<= 1) pr += __shfl_xor(pr, o);
            if (m == 0) atomicAdd(&dl[rowTile * 16 + q * 4 + r], pr);
        }
    }
}

// kG: logits = h_l @ u_l + b_l2 (fp32 [1024 x VP])
__global__ __launch_bounds__(256) void kG(
    const u16* __restrict__ hlH, const u16* __restrict__ hlL,
    const u16* __restrict__ uTh, const u16* __restrict__ uTl,
    const float* __restrict__ b_l2, float* __restrict__ logits) {
    __shared__ __align__(1024) u16 lds[2 * 8 * 512];
    int ctBase = blockIdx.y * 4;
    int rowTile = (blockIdx.x * 64 >> 4) + (threadIdx.x >> 6);
    f32x4 z4 = {0.f, 0.f, 0.f, 0.f};
    f32x4 acc[1][4] = {{z4, z4, z4, z4}};
    mfma_strip_lds<1>(hlH, hlL, 15, rowTile, uTh, uTl,
                      nullptr, nullptr, nullptr, nullptr, 15, ctBase, 15, lds, acc);
    int lane = threadIdx.x & 63, m = lane & 15, q = lane >> 4;
#pragma unroll
    for (int c = 0; c < 4; ++c) {
        int col = (ctBase + c) * 16 + m;
        if (col >= VOCAB) continue;
        float bl = b_l2[col];
#pragma unroll
        for (int r = 0; r < 4; ++r)
            logits[(size_t)(rowTile * 16 + q * 4 + r) * VP + col] = acc[0][c][r] + bl;
    }
}

// label CE from logits
__global__ __launch_bounds__(256) void k_ce(
    const float* __restrict__ logits, const int* __restrict__ label_t,
    float* __restrict__ out) {
    __shared__ float s_red[4];
    int base = blockIdx.x * 4, tid = threadIdx.x, lane = tid & 63, wave = tid >> 6;
    float ce = 0.0f;
    for (int r = 0; r < 4; ++r) {
        const float* lg = logits + (size_t)(base + r) * VP;
        float m = -INFINITY;
        for (int d = tid; d < VOCAB; d += 256) m = fmaxf(m, lg[d]);
#pragma unroll
        for (int o = 32; o; o >>= 1) m = fmaxf(m, __shfl_xor(m, o));
        if (lane == 0) s_red[wave] = m;
        __syncthreads();
        float m4 = fmaxf(fmaxf(s_red[0], s_red[1]), fmaxf(s_red[2], s_red[3]));
        __syncthreads();
        float s = 0.0f;
        for (int d = tid; d < VOCAB; d += 256) s += expf(lg[d] - m4);
#pragma unroll
        for (int o = 32; o; o >>= 1) s += __shfl_xor(s, o);
        if (lane == 0) s_red[wave] = s;
        __syncthreads();
        if (tid == 0) {
            float Z = s_red[0] + s_red[1] + s_red[2] + s_red[3];
            ce += (m4 + logf(Z)) - lg[label_t[base + r]];
        }
        __syncthreads();
    }
    if (tid == 0) atomicAdd(&out[1], ce);
}

// topology loss from dl
__global__ __launch_bounds__(1024) void k_topo_final(
    const float* __restrict__ dl, const float* __restrict__ b_d3,
    const float* __restrict__ topo_t, float* __restrict__ out) {
    __shared__ float s_red[16];
    int tid = threadIdx.x, lane = tid & 63, wave = tid >> 6;
    float v = dl[tid] + b_d3[0];
    float ce = softplusf_(v) - topo_t[tid] * v;
#pragma unroll
    for (int o = 32; o; o >>= 1) ce += __shfl_xor(ce, o);
    if (lane == 0) s_red[wave] = ce;
    __syncthreads();
    if (tid == 0) {
        float s = 0.f;
#pragma unroll
        for (int w = 0; w < 16; ++w) s += s_red[w];
        atomicAdd(&out[0], s);
    }
}

// ---------------------------------------------------------------------------
extern "C" void kernel_launch(void* const* d_in, const int* in_sizes, int n_in,
                              void* d_out, int out_size, void* d_ws, size_t ws_size,
                              hipStream_t stream) {
    const float* x_T       = (const float*)d_in[0];
    const float* x_G       = (const float*)d_in[1];
    const float* id_onehot = (const float*)d_in[2];
    // d_in[3] = msg0 (all zeros -> folded out)
    const float* emb   = (const float*)d_in[4];
    const float* wz    = (const float*)d_in[5];
    // 6 uz, 7 wr, 8 ur dead
    const float* w_h   = (const float*)d_in[9];
    // 10 u_h dead
    const float* bz    = (const float*)d_in[11];
    // 12 br dead
    const float* b_h   = (const float*)d_in[13];
    const float* w_d1  = (const float*)d_in[14];
    const float* w_d2  = (const float*)d_in[15];
    const float* b_d1  = (const float*)d_in[16];
    const float* a_dT  = (const float*)d_in[17];
    const float* a_dG  = (const float*)d_in[18];
    const float* w_d3  = (const float*)d_in[19];
    const float* w_d4  = (const float*)d_in[20];
    const float* b_d2  = (const float*)d_in[21];
    const float* u_d   = (const float*)d_in[22];
    const float* b_d3  = (const float*)d_in[23];
    const float* w_l1  = (const float*)d_in[24];
    const float* w_l2  = (const float*)d_in[25];
    const float* b_l1  = (const float*)d_in[26];
    const float* a_lT  = (const float*)d_in[27];
    const float* a_lG  = (const float*)d_in[28];
    const float* u_l   = (const float*)d_in[29];
    const float* b_l2  = (const float*)d_in[30];
    const float* topo_t = (const float*)d_in[31];
    const int* edge_src  = (const int*)d_in[32];
    // 33 edge_dst dead
    const int* lg_src    = (const int*)d_in[34];
    const int* lg_dst    = (const int*)d_in[35];
    const int* gid_T     = (const int*)d_in[36];
    const int* gid_G     = (const int*)d_in[37];
    const int* root_eids = (const int*)d_in[38];
    const int* label_t   = (const int*)d_in[39];
    float* out = (float*)d_out;

    char* p = (char*)d_ws;
    auto take = [&](size_t bytes) -> char* {
        char* r = p; p += (bytes + 255) & ~(size_t)255; return r;
    };
    // --- tiled weight arenas (hi/lo planes) ---
    const int SQ = WT_N * KP_D;                  // 245760 elements
    const int oWZ = 0, oWH = oWZ + SQ, oWD1 = oWH + SQ, oWD2 = oWD1 + SQ;
    const int oADT = oWD2 + SQ, oADG = oADT + SQ, oALT = oADG + SQ, oALG = oALT + SQ;
    const int oWCD = oALG + SQ;                  // 512 cols x 1440 k
    const int oWCL = oWCD + WT_N * CATP;
    const int oEMB = oWCL + WT_N * CATP;         // 512 cols x 800 k
    const int oUL  = oEMB + WT_N * KP_V;         // 832 cols x 480 k
    const int oEND = oUL + WT_NV * KP_D;
    u16* whi = (u16*)take((size_t)oEND * 2);
    u16* wlo = (u16*)take((size_t)oEND * 2);
    // --- tiled activation planes ---
    u16* idohH = (u16*)take((size_t)NROWA * KP_V * 2);
    u16* idohL = (u16*)take((size_t)NROWA * KP_V * 2);
    u16* fH    = (u16*)take((size_t)NROWA * KP_D * 2);
    u16* fL    = (u16*)take((size_t)NROWA * KP_D * 2);
    u16* sH    = (u16*)take((size_t)BGR * KP_D * 2);
    u16* sL    = (u16*)take((size_t)BGR * KP_D * 2);
    u16* cdH   = (u16*)take((size_t)BGR * CATP * 2);
    u16* cdL   = (u16*)take((size_t)BGR * CATP * 2);
    u16* clH   = (u16*)take((size_t)BGR * CATP * 2);
    u16* clL   = (u16*)take((size_t)BGR * CATP * 2);
    u16* hlH   = (u16*)take((size_t)BGR * KP_D * 2);
    u16* hlL   = (u16*)take((size_t)BGR * KP_D * 2);
    // --- fp32 intermediates ---
    const size_t BD = (size_t)BGR * DP * 4;
    float* sumh  = (float*)take(BD);
    float* fw1   = (float*)take(BD);
    float* qdT   = (float*)take(BD);
    float* qdG   = (float*)take(BD);
    float* qlT   = (float*)take(BD);
    float* qlG   = (float*)take(BD);
    float* logits = (float*)take((size_t)BGR * VP * 4);
    float* dl    = (float*)take((size_t)BGR * 4);
    int*  root_slot = (int*)take((size_t)NE * 4);
    int*  counter   = (int*)take(256);
    int2* tasks     = (int2*)take((size_t)CAP * 8);

    // --- weight prep jobs (transpose + split + fragment-tile + chunk-swizzle) ---
    WArgs wa; int cum = 0;
    auto addw = [&](int i, const float* src, int srcK, int srcN, int KpTot, int kOff,
                    int kLen, int NA, int dstOff) {
        wa.j[i] = WJob{src, srcK, srcN, KpTot, kOff, kLen, NA, dstOff, cum};
        cum += NA * kLen;
    };
    addw(0, wz,   D, D, KP_D, 0, KP_D, WT_N, oWZ);
    addw(1, w_h,  D, D, KP_D, 0, KP_D, WT_N, oWH);
    addw(2, w_d1, D, D, KP_D, 0, KP_D, WT_N, oWD1);
    addw(3, w_d2, D, D, KP_D, 0, KP_D, WT_N, oWD2);
    addw(4, a_dT, D, D, KP_D, 0, KP_D, WT_N, oADT);
    addw(5, a_dG, D, D, KP_D, 0, KP_D, WT_N, oADG);
    addw(6, a_lT, D, D, KP_D, 0, KP_D, WT_N, oALT);
    addw(7, a_lG, D, D, KP_D, 0, KP_D, WT_N, oALG);
    addw(8,  w_d3,                 D, D, CATP, 0,   KP_D, WT_N, oWCD);
    addw(9,  w_d4,                 D, D, CATP, 480, KP_D, WT_N, oWCD);
    addw(10, w_d4 + (size_t)D * D, D, D, CATP, 960, KP_D, WT_N, oWCD);
    addw(11, w_l1,                 D, D, CATP, 0,   KP_D, WT_N, oWCL);
    addw(12, w_l2,                 D, D, CATP, 480, KP_D, WT_N, oWCL);
    addw(13, w_l2 + (size_t)D * D, D, D, CATP, 960, KP_D, WT_N, oWCL);
    addw(14, emb, VOCAB, D, KP_V, 0, KP_V, WT_N, oEMB);
    addw(15, u_l, D, VOCAB, KP_D, 0, KP_D, WT_NV, oUL);
    wa.total = cum;

    k_prepw<<<2048, 256, 0, stream>>>(wa, whi, wlo);
    k_init<<<(BGR * DP + 255) / 256, 256, 0, stream>>>(sumh, root_slot, counter, dl, out);
    k_scatter_roots<<<(BGR + 255) / 256, 256, 0, stream>>>(root_eids, root_slot);
    k_build_tasks<<<(NELG + 255) / 256, 256, 0, stream>>>(lg_src, lg_dst, edge_src,
                                                          root_slot, tasks, counter);
    k_gather_idoh<<<4096, 256, 0, stream>>>(id_onehot, edge_src, root_eids, tasks,
                                            counter, idohH, idohL);
    kA<<<dim3(NROWA / 64, 8), 256, 0, stream>>>(idohH, idohL, whi + oEMB, wlo + oEMB,
                                                counter, fH, fL);
    kB<<<dim3(NROWA / 64, 8), 256, 0, stream>>>(fH, fL, whi + oWZ, wlo + oWZ,
                                                whi + oWH, wlo + oWH,
                                                whi + oWD1, wlo + oWD1, bz, b_h,
                                                tasks, counter, clH, clL, fw1, sumh);
    k_conv_sumh<<<(BGR * KP_D + 255) / 256, 256, 0, stream>>>(sumh, root_slot, root_eids, sH, sL);
    kC<<<dim3(16, 8), 256, 0, stream>>>(sH, sL, whi + oWD2, wlo + oWD2, fw1, b_d1, cdH, cdL);
    kD<<<dim3(16, 8, 2), 256, 0, stream>>>(cdH, cdL, clH, clL,
                                           whi + oADT, wlo + oADT, whi + oADG, wlo + oADG,
                                           whi + oALT, wlo + oALT, whi + oALG, wlo + oALG,
                                           qdT, qdG, qlT, qlG);
    k_att<<<2 * BGR, 256, 0, stream>>>(x_T, x_G, gid_T, gid_G, qdT, qdG, qlT, qlG,
                                       cdH, cdL, clH, clL);
    kEF<<<dim3(16, 8, 2), 256, 0, stream>>>(cdH, cdL, clH, clL,
                                            whi + oWCD, wlo + oWCD, whi + oWCL, wlo + oWCL,
                                            b_d2, u_d, b_l1, hlH, hlL, dl);
    k_topo_final<<<1, 1024, 0, stream>>>(dl, b_d3, topo_t, out);
    kG<<<dim3(16, 13), 256, 0, stream>>>(hlH, hlL, whi + oUL, wlo + oUL, b_l2, logits);
    k_ce<<<BGR / 4, 256, 0, stream>>>(logits, label_t, out);
}

// Round 2
// 794.306 us; speedup vs baseline: 1.0392x; 1.0105x over previous
//
#include <hip/hip_runtime.h>
#include <math.h>

// ---------------------------------------------------------------------------
// G2GDecoder forward loss on MI355X — R8: phase-overhead amortization.
//
// R7 post-mortem: strips were phase-overhead-bound (2 barriers + vmcnt drain
// + serial A-load wrapping only 12 MFMAs per kc). R8: R=2 row-tiling (kA/kB),
// A-register prefetch one kc ahead, depth-2 LDS staging pipeline (3 buffers,
// counted vmcnt), coalesced LDS-transpose k_prepw, and k_att row prefetch.
// All arithmetic orders unchanged -> bit-identical outputs.
// ---------------------------------------------------------------------------

#define BGR   1024
#define NT    51200
#define NG    61440
#define NE    100352
#define NELG  200704
#define D     450
#define DP    452       // fp32 intermediate row stride
#define KP_D  480       // bf16 K-pad for D-dim (mult of 32); ldT = 15
#define KP_V  800       // bf16 K-pad for vocab (780);        ldT = 25
#define CATP  1440      // 3*480 concat (segs at 0,480,960);  ldT = 45
#define VOCAB 780
#define VP    784
#define CAP   4096      // task cap; E[T]~2048
#define NROWA 5120      // BGR+CAP rows allocated for idoh/f planes
#define WT_N  512       // padded col count for D-out weights (32 col-tiles)
#define WT_NV 832       // padded col count for u_l (52 col-tiles)

typedef unsigned short u16;
typedef short bf16x8 __attribute__((ext_vector_type(8)));
typedef float f32x4 __attribute__((ext_vector_type(4)));

__device__ __forceinline__ float sigmoidf_(float x) { return 1.0f / (1.0f + expf(-x)); }
__device__ __forceinline__ float softplusf_(float x) {
    return fmaxf(x, 0.0f) + log1pf(expf(-fabsf(x)));   // == jax.nn.softplus
}
__device__ __forceinline__ int lower_bound_i(const int* __restrict__ a, int n, int v) {
    int lo = 0, hi = n;
    while (lo < hi) { int mid = (lo + hi) >> 1; if (a[mid] < v) lo = mid + 1; else hi = mid; }
    return lo;
}
__device__ __forceinline__ u16 f2bf(float x) {
    unsigned u = __float_as_uint(x);
    return (u16)((u + 0x7FFFu + ((u >> 16) & 1u)) >> 16);   // RNE
}
__device__ __forceinline__ float bf2f(u16 h) { return __uint_as_float(((unsigned)h) << 16); }
__device__ __forceinline__ void split2(float x, u16& h, u16& l) {
    h = f2bf(x); l = f2bf(x - bf2f(h));
}
__device__ __forceinline__ float dot4(float4 a, float4 b) {
    return fmaf(a.x, b.x, fmaf(a.y, b.y, fmaf(a.z, b.z, a.w * b.w)));
}
// fragment-tiled offset for logical (row, k) with ldT = Kp/32 tiles per row-strip
__device__ __forceinline__ size_t frag_off(int ldT, int row, int k) {
    return (((size_t)(row >> 4) * ldT + (k >> 5)) << 9) + ((row & 15) << 5) + (k & 31);
}

#define GLOAD_LDS16(SRC, DST)                                                   \
    __builtin_amdgcn_global_load_lds(                                           \
        (const __attribute__((address_space(1))) unsigned int*)(const void*)(SRC), \
        (__attribute__((address_space(3))) unsigned int*)(void*)(DST), 16, 0, 0)

// ---------------------------------------------------------------------------
// LDS-staged strip, R row-tiles per wave, depth-2 staging pipeline.
// Block = 256 thr / 4 waves; wave w owns rowTiles [rowTile0, rowTile0+R).
// All 4 waves share ctBase (4 col-tiles = 64 cols) and NW B-matrices.
// Per kc: NW*8 B tiles (hi+lo x 4 ct) staged into LDS buffer kc%3; stage for
// kc+2 and A-regs for kc+1 are issued BEFORE the counted vmcnt wait, so both
// overlap the MFMA cluster. acc[rt][n][c][r]: row=(rowTile0+rt)*16+(lane>>4)*4+r,
// col=(ctBase+c)*16+(lane&15).
template <int NW, int R>
__device__ __forceinline__ void mfma_strip_lds(
    const u16* Ah, const u16* Al, int ldTA, int rowTile0,
    const u16* Wh0, const u16* Wl0, const u16* Wh1, const u16* Wl1,
    const u16* Wh2, const u16* Wl2,
    int ldTW, int ctBase, int nKc, u16* lds, f32x4 (&acc)[R][NW][4]) {
    int lane = threadIdx.x & 63, wave = threadIdx.x >> 6;
    int m = lane & 15, q = lane >> 4;
    int lo = (m << 5) + (q << 3);
    const u16* pah[R]; const u16* pal[R];
#pragma unroll
    for (int r = 0; r < R; ++r) {
        pah[r] = Ah + (((size_t)(rowTile0 + r) * ldTA) << 9) + lo;
        pal[r] = Al + (((size_t)(rowTile0 + r) * ldTA) << 9) + lo;
    }
    // swizzled read offset (bytes) within a staged 1KB tile
    int boff = (m << 6) + (((q ^ ((m >> 1) & 3)) & 3) << 4);
    auto stage = [&](int kc) {
        int buf = kc % 3;
#pragma unroll
        for (int t = 0; t < 2 * NW; ++t) {
            int tile = wave + 4 * t;                 // 0 .. NW*8-1, wave-uniform
            int n = tile >> 3, c = (tile >> 1) & 3, pl = tile & 1;
            const u16* wp = (n == 0) ? (pl ? Wl0 : Wh0)
                          : (n == 1) ? (pl ? Wl1 : Wh1)
                                     : (pl ? Wl2 : Wh2);
            const u16* src = wp + ((((size_t)(ctBase + c)) * ldTW + kc) << 9) + (lane << 3);
            u16* dst = lds + (((size_t)(buf * NW * 8 + tile)) << 9);
            GLOAD_LDS16(src, dst);                   // 64 lanes x 16B = 1KB tile
        }
    };
    bf16x8 aH[R], aL[R], nH[R], nL[R];
    auto prefA = [&](int kc, bf16x8 (&H)[R], bf16x8 (&L)[R]) {
#pragma unroll
        for (int r = 0; r < R; ++r) {
            H[r] = *(const bf16x8*)(pah[r] + ((size_t)kc << 9));
            L[r] = *(const bf16x8*)(pal[r] + ((size_t)kc << 9));
        }
    };
    stage(0); stage(1);
    prefA(0, aH, aL);
    for (int kc = 0; kc < nKc; ++kc) {
        int rem = nKc - kc;
        if (rem > 2) stage(kc + 2);
        if (rem > 1) prefA(kc + 1, nH, nL);
        if (rem > 2) {
            asm volatile("s_waitcnt vmcnt(%0)" :: "n"(4 * NW + 2 * R) : "memory");
        } else if (rem > 1) {
            asm volatile("s_waitcnt vmcnt(%0)" :: "n"(2 * NW + 2 * R) : "memory");
        } else {
            asm volatile("s_waitcnt vmcnt(0)" ::: "memory");
        }
        __builtin_amdgcn_s_barrier();
        asm volatile("" ::: "memory");               // keep ds_reads below barrier
        const u16* tb = lds + (((size_t)((kc % 3) * NW * 8)) << 9);
#pragma unroll
        for (int n = 0; n < NW; ++n) {
#pragma unroll
            for (int c = 0; c < 4; ++c) {
                const char* bt = (const char*)(tb + (((n << 3) + (c << 1)) << 9));
                bf16x8 bH = *(const bf16x8*)(bt + boff);
                bf16x8 bL = *(const bf16x8*)(bt + 1024 + boff);
#pragma unroll
                for (int r = 0; r < R; ++r) {
                    acc[r][n][c] = __builtin_amdgcn_mfma_f32_16x16x32_bf16(aH[r], bH, acc[r][n][c], 0, 0, 0);
                    acc[r][n][c] = __builtin_amdgcn_mfma_f32_16x16x32_bf16(aH[r], bL, acc[r][n][c], 0, 0, 0);
                    acc[r][n][c] = __builtin_amdgcn_mfma_f32_16x16x32_bf16(aL[r], bH, acc[r][n][c], 0, 0, 0);
                }
            }
        }
        asm volatile("" ::: "memory");               // all reads done before restage
        __builtin_amdgcn_s_barrier();
        asm volatile("" ::: "memory");
        if (rem > 1) {
#pragma unroll
            for (int r = 0; r < R; ++r) { aH[r] = nH[r]; aL[r] = nL[r]; }
        }
    }
}

// ---------------------------------------------------------------------------
// Weight prep: dst tiled [colTile][kc] with col from src's N-dim (transpose),
// k range [kOff, kOff+kLen) of a KpTot-deep stacked buffer. Chunk-swizzled.
// R8: per-wave LDS transpose -> coalesced 64B global reads, contiguous 1KB
// tile writes. LDS padded x33 to avoid bank conflicts on both phases.
struct WJob { const float* src; int srcK, srcN, KpTot, kOff, kLen, NA, dstOff, cum; };
struct WArgs { WJob j[16]; int total; };

__global__ __launch_bounds__(256) void k_prepw(WArgs a, u16* __restrict__ whi,
                                               u16* __restrict__ wlo) {
    __shared__ float tl[4][544];                     // [wave][colL*33 + kL]
    int wave = threadIdx.x >> 6, lane = threadIdx.x & 63;
    int nTiles = a.total >> 9;
    for (int tileIdx = blockIdx.x * 4 + wave; tileIdx < nTiles;
         tileIdx += gridDim.x * 4) {
        int jj = 0;
        while (jj < 15 && tileIdx >= (a.j[jj + 1].cum >> 9)) ++jj;
        WJob J = a.j[jj];
        int t = tileIdx - (J.cum >> 9);
        int nKc = J.kLen >> 5;
        int ct = t / nKc, kcL = t - ct * nKc;
#pragma unroll
        for (int it = 0; it < 8; ++it) {             // load 512 src elems, coalesced
            int e = it * 64 + lane;
            int colL = e & 15, kLw = e >> 4;
            int kk = kcL * 32 + kLw;
            int col = ct * 16 + colL;
            float v = (kk < J.srcK && col < J.srcN) ? J.src[(size_t)kk * J.srcN + col] : 0.f;
            tl[wave][colL * 33 + kLw] = v;
        }
        size_t base = (size_t)J.dstOff
                    + (((size_t)(ct * (J.KpTot >> 5) + (J.kOff >> 5) + kcL)) << 9);
#pragma unroll
        for (int it = 0; it < 8; ++it) {             // write 512 u16 x2, contiguous
            int w = it * 64 + lane;
            int colL = w >> 5;
            int kL = ((((w >> 3) & 3) ^ ((colL >> 1) & 3)) << 3) | (w & 7);  // inv bswz
            u16 h, l; split2(tl[wave][colL * 33 + kL], h, l);
            whi[base + w] = h; wlo[base + w] = l;
        }
    }
}

__global__ void k_init(float* __restrict__ sumh, int* __restrict__ root_slot,
                       int* __restrict__ counter, float* __restrict__ dl,
                       float* __restrict__ out) {
    int i = blockIdx.x * blockDim.x + threadIdx.x;
    if (i < BGR * DP) sumh[i] = 0.0f;
    if (i < NE) root_slot[i] = -1;
    if (i < BGR) dl[i] = 0.0f;
    if (i == 0) counter[0] = 0;
    if (i < 2) out[i] = 0.0f;
}

__global__ void k_scatter_roots(const int* __restrict__ root_eids, int* __restrict__ root_slot) {
    int b = blockIdx.x * blockDim.x + threadIdx.x;
    if (b < BGR) root_slot[root_eids[b]] = b;   // duplicate roots share one slot
}

__global__ void k_build_tasks(const int* __restrict__ lg_src, const int* __restrict__ lg_dst,
                              const int* __restrict__ edge_src, const int* __restrict__ root_slot,
                              int2* __restrict__ tasks, int* __restrict__ counter) {
    int j = blockIdx.x * blockDim.x + threadIdx.x;
    if (j < NELG) {
        int r = root_slot[lg_dst[j]];
        if (r >= 0) {
            int idx = atomicAdd(counter, 1);
            if (idx < CAP) tasks[idx] = make_int2(edge_src[lg_src[j]], r);
        }
    }
}

// Gather id_onehot rows (roots then tasks) -> tiled hi/lo planes [NROWA x KP_V].
// A-operand layout: linear (NOT swizzled).
__global__ void k_gather_idoh(
    const float* __restrict__ id_onehot, const int* __restrict__ edge_src,
    const int* __restrict__ root_eids, const int2* __restrict__ tasks,
    const int* __restrict__ counter, u16* __restrict__ ih, u16* __restrict__ il) {
    int T = counter[0]; if (T > CAP) T = CAP;
    int nRows = BGR + T;
    long total = (long)NROWA * KP_V;
    long idx = (long)(blockIdx.x * blockDim.x + threadIdx.x);
    long stride = (long)gridDim.x * blockDim.x;
    for (; idx < total; idx += stride) {
        int t = (int)(idx >> 9), w = (int)(idx & 511);
        int rt = t / 25, kc = t - rt * 25;
        int row = rt * 16 + (w >> 5), k = kc * 32 + (w & 31);
        float v = 0.f;
        if (row < nRows && k < VOCAB) {
            int n = (row < BGR) ? edge_src[root_eids[row]] : tasks[row - BGR].x;
            v = id_onehot[(size_t)n * VOCAB + k];
        }
        u16 h, l; split2(v, h, l);
        ih[idx] = h; il[idx] = l;
    }
}

// Gather sumh rows by root slot -> tiled hi/lo [1024 x KP_D]. (A-operand, linear.)
__global__ void k_conv_sumh(
    const float* __restrict__ sumh, const int* __restrict__ root_slot,
    const int* __restrict__ root_eids, u16* __restrict__ sh, u16* __restrict__ sl) {
    int idx = blockIdx.x * blockDim.x + threadIdx.x;
    if (idx >= BGR * KP_D) return;
    int t = idx >> 9, w = idx & 511;
    int rt = t / 15, kc = t - rt * 15;
    int row = rt * 16 + (w >> 5), k = kc * 32 + (w & 31);
    int slot = root_slot[root_eids[row]];
    float v = (k < D) ? sumh[(size_t)slot * DP + k] : 0.f;
    u16 h, l; split2(v, h, l);
    sh[idx] = h; sl[idx] = l;
}

// ---------------------------------------------------------------------------
// kA: f[row] = idoh[row] @ emb -> f tiled [NROWA x KP_D].  R=2 row-tiles/wave.
__global__ __launch_bounds__(256) void kA(
    const u16* __restrict__ ih, const u16* __restrict__ il,
    const u16* __restrict__ eTh, const u16* __restrict__ eTl,
    const int* __restrict__ counter, u16* __restrict__ fH, u16* __restrict__ fL) {
    __shared__ __align__(1024) u16 lds[3 * 8 * 512];
    int T = counter[0]; if (T > CAP) T = CAP;
    int nRows = BGR + T;
    int rowBase = blockIdx.x * 128; if (rowBase >= nRows) return;
    int ctBase = blockIdx.y * 4;
    int rowTile0 = blockIdx.x * 8 + (threadIdx.x >> 6) * 2;
    f32x4 z4 = {0.f, 0.f, 0.f, 0.f};
    f32x4 acc[2][1][4] = {{{z4, z4, z4, z4}}, {{z4, z4, z4, z4}}};
    mfma_strip_lds<1, 2>(ih, il, 25, rowTile0, eTh, eTl, nullptr, nullptr, nullptr, nullptr,
                         25, ctBase, 25, lds, acc);
    int lane = threadIdx.x & 63, m = lane & 15, q = lane >> 4;
#pragma unroll
    for (int rt = 0; rt < 2; ++rt) {
#pragma unroll
        for (int c = 0; c < 4; ++c) {
            int col = (ctBase + c) * 16 + m;
            if (col >= KP_D) continue;
#pragma unroll
            for (int r = 0; r < 4; ++r) {
                int row = (rowTile0 + rt) * 16 + q * 4 + r;
                size_t o = frag_off(15, row, col);
                u16 h, l; split2(acc[rt][0][c][r], h, l);
                fH[o] = h; fL[o] = l;
            }
        }
    }
}

// kB: z=f@wz, hh=f@w_h (+ fw1=f@w_d1 for root tiles) — fused, A loaded once,
// R=2. Roots -> msg into catl seg0 (tiled) + fw1 (fp32); tasks -> atomic sumh.
__global__ __launch_bounds__(256) void kB(
    const u16* __restrict__ fH, const u16* __restrict__ fL,
    const u16* __restrict__ wzTh, const u16* __restrict__ wzTl,
    const u16* __restrict__ whTh, const u16* __restrict__ whTl,
    const u16* __restrict__ wd1Th, const u16* __restrict__ wd1Tl,
    const float* __restrict__ bz, const float* __restrict__ b_h,
    const int2* __restrict__ tasks, const int* __restrict__ counter,
    u16* __restrict__ clH, u16* __restrict__ clL,
    float* __restrict__ fw1, float* __restrict__ sumh) {
    __shared__ __align__(1024) u16 lds[3 * 3 * 8 * 512];
    int T = counter[0]; if (T > CAP) T = CAP;
    int nRows = BGR + T;
    int rowBase = blockIdx.x * 128; if (rowBase >= nRows) return;
    int ctBase = blockIdx.y * 4;
    int rowTile0 = blockIdx.x * 8 + (threadIdx.x >> 6) * 2;
    bool isRoot = rowBase < BGR;
    int lane = threadIdx.x & 63, m = lane & 15, q = lane >> 4;
    f32x4 z4 = {0.f, 0.f, 0.f, 0.f};
    if (isRoot) {
        f32x4 acc[2][3][4] = {{{z4, z4, z4, z4}, {z4, z4, z4, z4}, {z4, z4, z4, z4}},
                              {{z4, z4, z4, z4}, {z4, z4, z4, z4}, {z4, z4, z4, z4}}};
        mfma_strip_lds<3, 2>(fH, fL, 15, rowTile0, wzTh, wzTl, whTh, whTl, wd1Th, wd1Tl,
                             15, ctBase, 15, lds, acc);
#pragma unroll
        for (int rt = 0; rt < 2; ++rt) {
#pragma unroll
            for (int c = 0; c < 4; ++c) {
                int col = (ctBase + c) * 16 + m;
                if (col >= KP_D) continue;
                float bzv = (col < D) ? bz[col] : 0.f;
                float bhv = (col < D) ? b_h[col] : 0.f;
#pragma unroll
                for (int r = 0; r < 4; ++r) {
                    int row = (rowTile0 + rt) * 16 + q * 4 + r;
                    float v = (col < D)
                        ? sigmoidf_(acc[rt][0][c][r] + bzv) * tanhf(acc[rt][1][c][r] + bhv) : 0.f;
                    size_t o = frag_off(45, row, col);   // catl seg0: k = col
                    u16 h, l; split2(v, h, l);
                    clH[o] = h; clL[o] = l;
                    if (col < D) fw1[(size_t)row * DP + col] = acc[rt][2][c][r];
                }
            }
        }
    } else {
        f32x4 acc[2][2][4] = {{{z4, z4, z4, z4}, {z4, z4, z4, z4}},
                              {{z4, z4, z4, z4}, {z4, z4, z4, z4}}};
        mfma_strip_lds<2, 2>(fH, fL, 15, rowTile0, wzTh, wzTl, whTh, whTl, nullptr, nullptr,
                             15, ctBase, 15, lds, acc);
#pragma unroll
        for (int rt = 0; rt < 2; ++rt) {
#pragma unroll
            for (int c = 0; c < 4; ++c) {
                int col = (ctBase + c) * 16 + m;
                if (col >= D) continue;
                float bzv = bz[col], bhv = b_h[col];
#pragma unroll
                for (int r = 0; r < 4; ++r) {
                    int row = (rowTile0 + rt) * 16 + q * 4 + r;
                    if (row < nRows) {
                        float v = sigmoidf_(acc[rt][0][c][r] + bzv) * tanhf(acc[rt][1][c][r] + bhv);
                        int slot = tasks[row - BGR].y;
                        atomicAdd(&sumh[(size_t)slot * DP + col], v);
                    }
                }
            }
        }
    }
}

// kC: hroot = relu(fw1 + sumhs@w_d2 + b_d1) -> catd seg0 (tiled)
__global__ __launch_bounds__(256) void kC(
    const u16* __restrict__ sH, const u16* __restrict__ sL,
    const u16* __restrict__ wTh, const u16* __restrict__ wTl,
    const float* __restrict__ fw1, const float* __restrict__ b_d1,
    u16* __restrict__ cdH, u16* __restrict__ cdL) {
    __shared__ __align__(1024) u16 lds[3 * 8 * 512];
    int ctBase = blockIdx.y * 4;
    int rowTile0 = blockIdx.x * 4 + (threadIdx.x >> 6);
    f32x4 z4 = {0.f, 0.f, 0.f, 0.f};
    f32x4 acc[1][1][4] = {{{z4, z4, z4, z4}}};
    mfma_strip_lds<1, 1>(sH, sL, 15, rowTile0, wTh, wTl, nullptr, nullptr, nullptr, nullptr,
                         15, ctBase, 15, lds, acc);
    int lane = threadIdx.x & 63, m = lane & 15, q = lane >> 4;
#pragma unroll
    for (int c = 0; c < 4; ++c) {
        int col = (ctBase + c) * 16 + m;
        if (col >= KP_D) continue;
        float bd = (col < D) ? b_d1[col] : 0.f;
#pragma unroll
        for (int r = 0; r < 4; ++r) {
            int row = rowTile0 * 16 + q * 4 + r;
            float v = 0.f;
            if (col < D) v = fmaxf(fw1[(size_t)row * DP + col] + acc[0][0][c][r] + bd, 0.f);
            size_t o = frag_off(45, row, col);
            u16 h, l; split2(v, h, l);
            cdH[o] = h; cdL[o] = l;
        }
    }
}

// kD: job0: catd seg0 @ {a_dT,a_dG} -> qdT,qdG ; job1: catl seg0 @ {a_lT,a_lG}
__global__ __launch_bounds__(256) void kD(
    const u16* __restrict__ cdH, const u16* __restrict__ cdL,
    const u16* __restrict__ clH, const u16* __restrict__ clL,
    const u16* __restrict__ aTh0, const u16* __restrict__ aTl0,
    const u16* __restrict__ aGh0, const u16* __restrict__ aGl0,
    const u16* __restrict__ aTh1, const u16* __restrict__ aTl1,
    const u16* __restrict__ aGh1, const u16* __restrict__ aGl1,
    float* __restrict__ qdT, float* __restrict__ qdG,
    float* __restrict__ qlT, float* __restrict__ qlG) {
    __shared__ __align__(1024) u16 lds[3 * 2 * 8 * 512];
    int ctBase = blockIdx.y * 4, job = blockIdx.z;
    int rowTile0 = blockIdx.x * 4 + (threadIdx.x >> 6);
    const u16* Ahp = job ? clH : cdH;
    const u16* Alp = job ? clL : cdL;
    f32x4 z4 = {0.f, 0.f, 0.f, 0.f};
    f32x4 acc[1][2][4] = {{{z4, z4, z4, z4}, {z4, z4, z4, z4}}};
    mfma_strip_lds<2, 1>(Ahp, Alp, 45, rowTile0,
                         job ? aTh1 : aTh0, job ? aTl1 : aTl0,
                         job ? aGh1 : aGh0, job ? aGl1 : aGl0,
                         nullptr, nullptr, 15, ctBase, 15, lds, acc);
    float* oT = job ? qlT : qdT;
    float* oG = job ? qlG : qdG;
    int lane = threadIdx.x & 63, m = lane & 15, q = lane >> 4;
#pragma unroll
    for (int c = 0; c < 4; ++c) {
        int col = (ctBase + c) * 16 + m;
        if (col >= D) continue;
#pragma unroll
        for (int r = 0; r < 4; ++r) {
            int row = rowTile0 * 16 + q * 4 + r;
            oT[(size_t)row * DP + col] = acc[0][0][c][r];
            oG[(size_t)row * DP + col] = acc[0][1][c][r];
        }
    }
}

// Fused dual attention, single-pass online softmax, float4 x-loads, 1-deep
// row prefetch (HBM latency hidden under shfl-reduce chain).
__global__ __launch_bounds__(256) void k_att(
    const float* __restrict__ x_T, const float* __restrict__ x_G,
    const int* __restrict__ gid_T, const int* __restrict__ gid_G,
    const float* __restrict__ qdT, const float* __restrict__ qdG,
    const float* __restrict__ qlT, const float* __restrict__ qlG,
    u16* __restrict__ cdH, u16* __restrict__ cdL,
    u16* __restrict__ clH, u16* __restrict__ clL) {
    int bid = blockIdx.x, b = bid & (BGR - 1), which = bid >> 10;
    const float* x   = which ? x_G   : x_T;
    const int*   gid = which ? gid_G : gid_T;
    int N            = which ? NG    : NT;
    const float* qd  = (which ? qdG : qdT) + (size_t)b * DP;
    const float* ql  = (which ? qlG : qlT) + (size_t)b * DP;
    int K0 = 480 + which * 480;
    int tid = threadIdx.x, lane = tid & 63, wave = tid >> 6;
    __shared__ __align__(16) float s_qd[DP], s_ql[DP];
    __shared__ float s_m[4][2], s_z[4][2];
    __shared__ __align__(16) float s_acc[4][2][DP];
    for (int d = tid; d < DP; d += 256) {
        s_qd[d] = (d < D) ? qd[d] : 0.f;
        s_ql[d] = (d < D) ? ql[d] : 0.f;
    }
    int lo = lower_bound_i(gid, N, b), hi = lower_bound_i(gid, N, b + 1);
    __syncthreads();
    int g0 = lane, g1 = 64 + lane;
    bool g1ok = g1 < 112;                       // 112 full float4 groups (448)
    bool tok = (lane == 48) || (lane == 49);    // tail d = 448, 449
    int td = 448 + (lane - 48);
    float4 qd0 = *(const float4*)&s_qd[4 * g0];
    float4 ql0 = *(const float4*)&s_ql[4 * g0];
    float4 qd1 = g1ok ? *(const float4*)&s_qd[4 * g1] : make_float4(0, 0, 0, 0);
    float4 ql1 = g1ok ? *(const float4*)&s_ql[4 * g1] : make_float4(0, 0, 0, 0);
    float tqd = tok ? s_qd[td] : 0.f, tql = tok ? s_ql[td] : 0.f;
    float md = -INFINITY, ml = -INFINITY, zd = 0.f, zl = 0.f;
    float4 ad0 = make_float4(0, 0, 0, 0), ad1 = ad0, al0 = ad0, al1 = ad0;
    float atd = 0.f, atl = 0.f;
    int n = lo + wave;
    float4 v0 = make_float4(0, 0, 0, 0), v1 = v0; float tv = 0.f;
    if (n < hi) {
        const float* xr = x + (size_t)n * D;
        v0 = *(const float4*)(xr + 4 * g0);
        v1 = g1ok ? *(const float4*)(xr + 4 * g1) : make_float4(0, 0, 0, 0);
        tv = tok ? xr[td] : 0.f;
    }
    for (; n < hi; n += 4) {
        float4 w0 = make_float4(0, 0, 0, 0), w1 = w0; float wv = 0.f;
        int nn = n + 4;
        if (nn < hi) {                           // prefetch next row for this wave
            const float* xr = x + (size_t)nn * D;
            w0 = *(const float4*)(xr + 4 * g0);
            w1 = g1ok ? *(const float4*)(xr + 4 * g1) : make_float4(0, 0, 0, 0);
            wv = tok ? xr[td] : 0.f;
        }
        float pd = dot4(v0, qd0) + dot4(v1, qd1) + tv * tqd;
        float pl = dot4(v0, ql0) + dot4(v1, ql1) + tv * tql;
#pragma unroll
        for (int o = 32; o; o >>= 1) { pd += __shfl_xor(pd, o); pl += __shfl_xor(pl, o); }
        float nmd = fmaxf(md, pd), nml = fmaxf(ml, pl);
        float sd = expf(md - nmd), sl = expf(ml - nml);
        float ed = expf(pd - nmd), el = expf(pl - nml);
        zd = zd * sd + ed; zl = zl * sl + el;
        ad0.x = ad0.x * sd + ed * v0.x; ad0.y = ad0.y * sd + ed * v0.y;
        ad0.z = ad0.z * sd + ed * v0.z; ad0.w = ad0.w * sd + ed * v0.w;
        ad1.x = ad1.x * sd + ed * v1.x; ad1.y = ad1.y * sd + ed * v1.y;
        ad1.z = ad1.z * sd + ed * v1.z; ad1.w = ad1.w * sd + ed * v1.w;
        al0.x = al0.x * sl + el * v0.x; al0.y = al0.y * sl + el * v0.y;
        al0.z = al0.z * sl + el * v0.z; al0.w = al0.w * sl + el * v0.w;
        al1.x = al1.x * sl + el * v1.x; al1.y = al1.y * sl + el * v1.y;
        al1.z = al1.z * sl + el * v1.z; al1.w = al1.w * sl + el * v1.w;
        atd = atd * sd + ed * tv; atl = atl * sl + el * tv;
        md = nmd; ml = nml;
        v0 = w0; v1 = w1; tv = wv;
    }
    *(float4*)&s_acc[wave][0][4 * g0] = ad0;
    *(float4*)&s_acc[wave][1][4 * g0] = al0;
    if (g1ok) {
        *(float4*)&s_acc[wave][0][4 * g1] = ad1;
        *(float4*)&s_acc[wave][1][4 * g1] = al1;
    }
    if (tok) { s_acc[wave][0][td] = atd; s_acc[wave][1][td] = atl; }
    if (lane == 0) { s_m[wave][0] = md; s_m[wave][1] = ml; s_z[wave][0] = zd; s_z[wave][1] = zl; }
    __syncthreads();
    bool nonempty = (hi > lo);
    float Md = fmaxf(fmaxf(s_m[0][0], s_m[1][0]), fmaxf(s_m[2][0], s_m[3][0]));
    float Ml = fmaxf(fmaxf(s_m[0][1], s_m[1][1]), fmaxf(s_m[2][1], s_m[3][1]));
    float scd[4], scl[4];
#pragma unroll
    for (int w = 0; w < 4; ++w) { scd[w] = expf(s_m[w][0] - Md); scl[w] = expf(s_m[w][1] - Ml); }
    float Zd = s_z[0][0] * scd[0] + s_z[1][0] * scd[1] + s_z[2][0] * scd[2] + s_z[3][0] * scd[3];
    float Zl = s_z[0][1] * scl[0] + s_z[1][1] * scl[1] + s_z[2][1] * scl[2] + s_z[3][1] * scl[3];
    for (int d = tid; d < KP_D; d += 256) {
        float av = 0.f, lv = 0.f;
        if (d < D && nonempty) {
            av = (s_acc[0][0][d] * scd[0] + s_acc[1][0][d] * scd[1]
                + s_acc[2][0][d] * scd[2] + s_acc[3][0][d] * scd[3]) / Zd;
            lv = (s_acc[0][1][d] * scl[0] + s_acc[1][1][d] * scl[1]
                + s_acc[2][1][d] * scl[2] + s_acc[3][1][d] * scl[3]) / Zl;
        }
        size_t o = frag_off(45, b, K0 + d);
        u16 h, l;
        split2(av, h, l); cdH[o] = h; cdL[o] = l;
        split2(lv, h, l); clH[o] = h; clL[o] = l;
    }
}

// kEF: job0 topo head (K=1440 -> relu.u_d partial dot -> dl); job1 label hidden.
__global__ __launch_bounds__(256) void kEF(
    const u16* __restrict__ cdH, const u16* __restrict__ cdL,
    const u16* __restrict__ clH, const u16* __restrict__ clL,
    const u16* __restrict__ wdTh, const u16* __restrict__ wdTl,
    const u16* __restrict__ wlTh, const u16* __restrict__ wlTl,
    const float* __restrict__ b_d2, const float* __restrict__ u_d,
    const float* __restrict__ b_l1,
    u16* __restrict__ hlH, u16* __restrict__ hlL, float* __restrict__ dl) {
    __shared__ __align__(1024) u16 lds[3 * 8 * 512];
    int ctBase = blockIdx.y * 4, job = blockIdx.z;
    int rowTile0 = blockIdx.x * 4 + (threadIdx.x >> 6);
    f32x4 z4 = {0.f, 0.f, 0.f, 0.f};
    f32x4 acc[1][1][4] = {{{z4, z4, z4, z4}}};
    mfma_strip_lds<1, 1>(job ? clH : cdH, job ? clL : cdL, 45, rowTile0,
                         job ? wlTh : wdTh, job ? wlTl : wdTl,
                         nullptr, nullptr, nullptr, nullptr, 45, ctBase, 45, lds, acc);
    int lane = threadIdx.x & 63, m = lane & 15, q = lane >> 4;
    if (job) {
#pragma unroll
        for (int c = 0; c < 4; ++c) {
            int col = (ctBase + c) * 16 + m;
            if (col >= KP_D) continue;
            float b1 = (col < D) ? b_l1[col] : 0.f;
#pragma unroll
            for (int r = 0; r < 4; ++r) {
                int row = rowTile0 * 16 + q * 4 + r;
                float v = (col < D) ? fmaxf(acc[0][0][c][r] + b1, 0.f) : 0.f;
                size_t o = frag_off(15, row, col);
                u16 h, l; split2(v, h, l);
                hlH[o] = h; hlL[o] = l;
            }
        }
    } else {
#pragma unroll
        for (int r = 0; r < 4; ++r) {
            float pr = 0.f;
#pragma unroll
            for (int c = 0; c < 4; ++c) {
                int col = (ctBase + c) * 16 + m;
                if (col < D) pr += fmaxf(acc[0][0][c][r] + b_d2[col], 0.f) * u_d[col];
            }
#pragma unroll
            for (int o = 1; o < 16; o <<= 1) pr += __shfl_xor(pr, o);
            if (m == 0) atomicAdd(&dl[rowTile0 * 16 + q * 4 + r], pr);
        }
    }
}

// kG: logits = h_l @ u_l + b_l2 (fp32 [1024 x VP])
__global__ __launch_bounds__(256) void kG(
    const u16* __restrict__ hlH, const u16* __restrict__ hlL,
    const u16* __restrict__ uTh, const u16* __restrict__ uTl,
    const float* __restrict__ b_l2, float* __restrict__ logits) {
    __shared__ __align__(1024) u16 lds[3 * 8 * 512];
    int ctBase = blockIdx.y * 4;
    int rowTile0 = blockIdx.x * 4 + (threadIdx.x >> 6);
    f32x4 z4 = {0.f, 0.f, 0.f, 0.f};
    f32x4 acc[1][1][4] = {{{z4, z4, z4, z4}}};
    mfma_strip_lds<1, 1>(hlH, hlL, 15, rowTile0, uTh, uTl,
                         nullptr, nullptr, nullptr, nullptr, 15, ctBase, 15, lds, acc);
    int lane = threadIdx.x & 63, m = lane & 15, q = lane >> 4;
#pragma unroll
    for (int c = 0; c < 4; ++c) {
        int col = (ctBase + c) * 16 + m;
        if (col >= VOCAB) continue;
        float bl = b_l2[col];
#pragma unroll
        for (int r = 0; r < 4; ++r)
            logits[(size_t)(rowTile0 * 16 + q * 4 + r) * VP + col] = acc[0][0][c][r] + bl;
    }
}

// label CE from logits
__global__ __launch_bounds__(256) void k_ce(
    const float* __restrict__ logits, const int* __restrict__ label_t,
    float* __restrict__ out) {
    __shared__ float s_red[4];
    int base = blockIdx.x * 4, tid = threadIdx.x, lane = tid & 63, wave = tid >> 6;
    float ce = 0.0f;
    for (int r = 0; r < 4; ++r) {
        const float* lg = logits + (size_t)(base + r) * VP;
        float m = -INFINITY;
        for (int d = tid; d < VOCAB; d += 256) m = fmaxf(m, lg[d]);
#pragma unroll
        for (int o = 32; o; o >>= 1) m = fmaxf(m, __shfl_xor(m, o));
        if (lane == 0) s_red[wave] = m;
        __syncthreads();
        float m4 = fmaxf(fmaxf(s_red[0], s_red[1]), fmaxf(s_red[2], s_red[3]));
        __syncthreads();
        float s = 0.0f;
        for (int d = tid; d < VOCAB; d += 256) s += expf(lg[d] - m4);
#pragma unroll
        for (int o = 32; o; o >>= 1) s += __shfl_xor(s, o);
        if (lane == 0) s_red[wave] = s;
        __syncthreads();
        if (tid == 0) {
            float Z = s_red[0] + s_red[1] + s_red[2] + s_red[3];
            ce += (m4 + logf(Z)) - lg[label_t[base + r]];
        }
        __syncthreads();
    }
    if (tid == 0) atomicAdd(&out[1], ce);
}

// topology loss from dl
__global__ __launch_bounds__(1024) void k_topo_final(
    const float* __restrict__ dl, const float* __restrict__ b_d3,
    const float* __restrict__ topo_t, float* __restrict__ out) {
    __shared__ float s_red[16];
    int tid = threadIdx.x, lane = tid & 63, wave = tid >> 6;
    float v = dl[tid] + b_d3[0];
    float ce = softplusf_(v) - topo_t[tid] * v;
#pragma unroll
    for (int o = 32; o; o >>= 1) ce += __shfl_xor(ce, o);
    if (lane == 0) s_red[wave] = ce;
    __syncthreads();
    if (tid == 0) {
        float s = 0.f;
#pragma unroll
        for (int w = 0; w < 16; ++w) s += s_red[w];
        atomicAdd(&out[0], s);
    }
}

// ---------------------------------------------------------------------------
extern "C" void kernel_launch(void* const* d_in, const int* in_sizes, int n_in,
                              void* d_out, int out_size, void* d_ws, size_t ws_size,
                              hipStream_t stream) {
    const float* x_T       = (const float*)d_in[0];
    const float* x_G       = (const float*)d_in[1];
    const float* id_onehot = (const float*)d_in[2];
    // d_in[3] = msg0 (all zeros -> folded out)
    const float* emb   = (const float*)d_in[4];
    const float* wz    = (const float*)d_in[5];
    // 6 uz, 7 wr, 8 ur dead
    const float* w_h   = (const float*)d_in[9];
    // 10 u_h dead
    const float* bz    = (const float*)d_in[11];
    // 12 br dead
    const float* b_h   = (const float*)d_in[13];
    const float* w_d1  = (const float*)d_in[14];
    const float* w_d2  = (const float*)d_in[15];
    const float* b_d1  = (const float*)d_in[16];
    const float* a_dT  = (const float*)d_in[17];
    const float* a_dG  = (const float*)d_in[18];
    const float* w_d3  = (const float*)d_in[19];
    const float* w_d4  = (const float*)d_in[20];
    const float* b_d2  = (const float*)d_in[21];
    const float* u_d   = (const float*)d_in[22];
    const float* b_d3  = (const float*)d_in[23];
    const float* w_l1  = (const float*)d_in[24];
    const float* w_l2  = (const float*)d_in[25];
    const float* b_l1  = (const float*)d_in[26];
    const float* a_lT  = (const float*)d_in[27];
    const float* a_lG  = (const float*)d_in[28];
    const float* u_l   = (const float*)d_in[29];
    const float* b_l2  = (const float*)d_in[30];
    const float* topo_t = (const float*)d_in[31];
    const int* edge_src  = (const int*)d_in[32];
    // 33 edge_dst dead
    const int* lg_src    = (const int*)d_in[34];
    const int* lg_dst    = (const int*)d_in[35];
    const int* gid_T     = (const int*)d_in[36];
    const int* gid_G     = (const int*)d_in[37];
    const int* root_eids = (const int*)d_in[38];
    const int* label_t   = (const int*)d_in[39];
    float* out = (float*)d_out;

    char* p = (char*)d_ws;
    auto take = [&](size_t bytes) -> char* {
        char* r = p; p += (bytes + 255) & ~(size_t)255; return r;
    };
    // --- tiled weight arenas (hi/lo planes) ---
    const int SQ = WT_N * KP_D;                  // 245760 elements
    const int oWZ = 0, oWH = oWZ + SQ, oWD1 = oWH + SQ, oWD2 = oWD1 + SQ;
    const int oADT = oWD2 + SQ, oADG = oADT + SQ, oALT = oADG + SQ, oALG = oALT + SQ;
    const int oWCD = oALG + SQ;                  // 512 cols x 1440 k
    const int oWCL = oWCD + WT_N * CATP;
    const int oEMB = oWCL + WT_N * CATP;         // 512 cols x 800 k
    const int oUL  = oEMB + WT_N * KP_V;         // 832 cols x 480 k
    const int oEND = oUL + WT_NV * KP_D;
    u16* whi = (u16*)take((size_t)oEND * 2);
    u16* wlo = (u16*)take((size_t)oEND * 2);
    // --- tiled activation planes ---
    u16* idohH = (u16*)take((size_t)NROWA * KP_V * 2);
    u16* idohL = (u16*)take((size_t)NROWA * KP_V * 2);
    u16* fH    = (u16*)take((size_t)NROWA * KP_D * 2);
    u16* fL    = (u16*)take((size_t)NROWA * KP_D * 2);
    u16* sH    = (u16*)take((size_t)BGR * KP_D * 2);
    u16* sL    = (u16*)take((size_t)BGR * KP_D * 2);
    u16* cdH   = (u16*)take((size_t)BGR * CATP * 2);
    u16* cdL   = (u16*)take((size_t)BGR * CATP * 2);
    u16* clH   = (u16*)take((size_t)BGR * CATP * 2);
    u16* clL   = (u16*)take((size_t)BGR * CATP * 2);
    u16* hlH   = (u16*)take((size_t)BGR * KP_D * 2);
    u16* hlL   = (u16*)take((size_t)BGR * KP_D * 2);
    // --- fp32 intermediates ---
    const size_t BD = (size_t)BGR * DP * 4;
    float* sumh  = (float*)take(BD);
    float* fw1   = (float*)take(BD);
    float* qdT   = (float*)take(BD);
    float* qdG   = (float*)take(BD);
    float* qlT   = (float*)take(BD);
    float* qlG   = (float*)take(BD);
    float* logits = (float*)take((size_t)BGR * VP * 4);
    float* dl    = (float*)take((size_t)BGR * 4);
    int*  root_slot = (int*)take((size_t)NE * 4);
    int*  counter   = (int*)take(256);
    int2* tasks     = (int2*)take((size_t)CAP * 8);

    // --- weight prep jobs (transpose + split + fragment-tile + chunk-swizzle) ---
    WArgs wa; int cum = 0;
    auto addw = [&](int i, const float* src, int srcK, int srcN, int KpTot, int kOff,
                    int kLen, int NA, int dstOff) {
        wa.j[i] = WJob{src, srcK, srcN, KpTot, kOff, kLen, NA, dstOff, cum};
        cum += NA * kLen;
    };
    addw(0, wz,   D, D, KP_D, 0, KP_D, WT_N, oWZ);
    addw(1, w_h,  D, D, KP_D, 0, KP_D, WT_N, oWH);
    addw(2, w_d1, D, D, KP_D, 0, KP_D, WT_N, oWD1);
    addw(3, w_d2, D, D, KP_D, 0, KP_D, WT_N, oWD2);
    addw(4, a_dT, D, D, KP_D, 0, KP_D, WT_N, oADT);
    addw(5, a_dG, D, D, KP_D, 0, KP_D, WT_N, oADG);
    addw(6, a_lT, D, D, KP_D, 0, KP_D, WT_N, oALT);
    addw(7, a_lG, D, D, KP_D, 0, KP_D, WT_N, oALG);
    addw(8,  w_d3,                 D, D, CATP, 0,   KP_D, WT_N, oWCD);
    addw(9,  w_d4,                 D, D, CATP, 480, KP_D, WT_N, oWCD);
    addw(10, w_d4 + (size_t)D * D, D, D, CATP, 960, KP_D, WT_N, oWCD);
    addw(11, w_l1,                 D, D, CATP, 0,   KP_D, WT_N, oWCL);
    addw(12, w_l2,                 D, D, CATP, 480, KP_D, WT_N, oWCL);
    addw(13, w_l2 + (size_t)D * D, D, D, CATP, 960, KP_D, WT_N, oWCL);
    addw(14, emb, VOCAB, D, KP_V, 0, KP_V, WT_N, oEMB);
    addw(15, u_l, D, VOCAB, KP_D, 0, KP_D, WT_NV, oUL);
    wa.total = cum;

    k_prepw<<<1024, 256, 0, stream>>>(wa, whi, wlo);
    k_init<<<(BGR * DP + 255) / 256, 256, 0, stream>>>(sumh, root_slot, counter, dl, out);
    k_scatter_roots<<<(BGR + 255) / 256, 256, 0, stream>>>(root_eids, root_slot);
    k_build_tasks<<<(NELG + 255) / 256, 256, 0, stream>>>(lg_src, lg_dst, edge_src,
                                                          root_slot, tasks, counter);
    k_gather_idoh<<<4096, 256, 0, stream>>>(id_onehot, edge_src, root_eids, tasks,
                                            counter, idohH, idohL);
    kA<<<dim3(NROWA / 128, 8), 256, 0, stream>>>(idohH, idohL, whi + oEMB, wlo + oEMB,
                                                 counter, fH, fL);
    kB<<<dim3(NROWA / 128, 8), 256, 0, stream>>>(fH, fL, whi + oWZ, wlo + oWZ,
                                                 whi + oWH, wlo + oWH,
                                                 whi + oWD1, wlo + oWD1, bz, b_h,
                                                 tasks, counter, clH, clL, fw1, sumh);
    k_conv_sumh<<<(BGR * KP_D + 255) / 256, 256, 0, stream>>>(sumh, root_slot, root_eids, sH, sL);
    kC<<<dim3(16, 8), 256, 0, stream>>>(sH, sL, whi + oWD2, wlo + oWD2, fw1, b_d1, cdH, cdL);
    kD<<<dim3(16, 8, 2), 256, 0, stream>>>(cdH, cdL, clH, clL,
                                           whi + oADT, wlo + oADT, whi + oADG, wlo + oADG,
                                           whi + oALT, wlo + oALT, whi + oALG, wlo + oALG,
                                           qdT, qdG, qlT, qlG);
    k_att<<<2 * BGR, 256, 0, stream>>>(x_T, x_G, gid_T, gid_G, qdT, qdG, qlT, qlG,
                                       cdH, cdL, clH, clL);
    kEF<<<dim3(16, 8, 2), 256, 0, stream>>>(cdH, cdL, clH, clL,
                                            whi + oWCD, wlo + oWCD, whi + oWCL, wlo + oWCL,
                                            b_d2, u_d, b_l1, hlH, hlL, dl);
    k_topo_final<<<1, 1024, 0, stream>>>(dl, b_d3, topo_t, out);
    kG<<<dim3(16, 13), 256, 0, stream>>>(hlH, hlL, whi + oUL, wlo + oUL, b_l2, logits);
    k_ce<<<BGR / 4, 256, 0, stream>>>(logits, label_t, out);
}